// Round 10
// baseline (239.899 us; speedup 1.0000x reference)
//
#include <hip/hip_runtime.h>

#define BB 4
#define LS 160
#define LW 128
#define DD 768
#define NSPANS 996
#define NZv 64
#define NPAIR 4096
#define HID 128
#define XLD 832          // X row stride: 768 feats + 64 pos
#define PROJ_N 393216    // 6*BB*LW*HID

// ---------- helpers ----------

__device__ inline void span_decode(int s, int& st, int& en, int& w) {
  int ww = 1, base = 0;
  while (ww < 8 && s >= base + (129 - ww)) { base += 129 - ww; ++ww; }
  st = s - base; en = st + ww - 1; w = ww;
}

__device__ inline int bucket17(int v) {
  const int BINSv[17] = {0,1,2,3,4,5,6,7,8,9,10,15,20,25,30,50,80};
  int r = 0;
#pragma unroll
  for (int k = 1; k < 17; ++k) r += (v >= BINSv[k]) ? 1 : 0;
  return r;
}

// ---------- kernel 1: prep = feats (96 blocks) + posfill (8) + smalltab (5) ----------
__global__ __launch_bounds__(256) void prep_kernel(
    const float* __restrict__ mask, const float* __restrict__ lh,
    const int* __restrict__ fss, const float* __restrict__ wlen,
    const int* __restrict__ pos_id, const float* __restrict__ pos_table,
    const float* __restrict__ width_table, const float* __restrict__ rel_table,
    const float* __restrict__ dep_table, const float* __restrict__ sW1,
    const float* __restrict__ pW1, const float* __restrict__ sb1,
    const float* __restrict__ pb1, float* __restrict__ X,
    float* __restrict__ tabs) {
  int gid = blockIdx.x;
  int tid = threadIdx.x;
  if (gid < 96) {
    int nt = gid % 12, mt = gid / 12;
    int b = mt >> 1;
    int row0 = mt * 64, c0 = nt * 64;
    __shared__ float as[16][68];   // [k][row]
    __shared__ float bs[16][68];   // [k][col]
    __shared__ int fssl[64];
    __shared__ float wll[64];
    if (tid < 64) { fssl[tid] = fss[row0 + tid]; wll[tid] = wlen[row0 + tid]; }
    __syncthreads();
    int rg = tid >> 4, tc = tid & 15;
    float acc[4][4] = {{0.f}};
    for (int k0 = 0; k0 < LS; k0 += 16) {
      {
        int r = tid >> 2, kb = (tid & 3) * 4;
        float4 mv = *(const float4*)(mask + (size_t)(b * LS + fssl[r]) * LS + k0 + kb);
        as[kb + 0][r] = mv.x; as[kb + 1][r] = mv.y;
        as[kb + 2][r] = mv.z; as[kb + 3][r] = mv.w;
      }
      {
        int c = tid & 63, kq = tid >> 6;
#pragma unroll
        for (int q = 0; q < 4; ++q) {
          int kk = kq * 4 + q;
          bs[kk][c] = lh[(size_t)(b * LS + k0 + kk) * DD + c0 + c];
        }
      }
      __syncthreads();
#pragma unroll
      for (int kk = 0; kk < 16; ++kk) {
        float av[4], bv[4];
#pragma unroll
        for (int i = 0; i < 4; ++i) av[i] = as[kk][rg * 4 + i];
#pragma unroll
        for (int j = 0; j < 4; ++j) bv[j] = bs[kk][tc * 4 + j];
#pragma unroll
        for (int i = 0; i < 4; ++i)
#pragma unroll
          for (int j = 0; j < 4; ++j) acc[i][j] += av[i] * bv[j];
      }
      __syncthreads();
    }
#pragma unroll
    for (int i = 0; i < 4; ++i) {
      int r = rg * 4 + i;
      float wl = wll[r];
      float4 v = make_float4(acc[i][0] / wl, acc[i][1] / wl, acc[i][2] / wl, acc[i][3] / wl);
      *(float4*)(X + (size_t)(row0 + r) * XLD + c0 + tc * 4) = v;
    }
  } else if (gid < 104) {
    int e0 = (gid - 96) * 4096 + tid * 16;
    int row = e0 >> 6, c0 = e0 & 63;
    const float* src = pos_table + pos_id[row] * 64 + c0;
    float* dst = X + (size_t)row * XLD + 768 + c0;
#pragma unroll
    for (int q = 0; q < 4; ++q)
      *(float4*)(dst + q * 4) = *(const float4*)(src + q * 4);
  } else {
    int bt = gid - 104;
    const float *src, *W, *bias; int rows; float* o;
    switch (bt) {
      case 0: src = width_table; W = sW1 + 1664 * HID; bias = sb1;    rows = 17; o = tabs;        break;
      case 1: src = width_table; W = pW1 + 1664 * HID; bias = nullptr; rows = 17; o = tabs + 2176; break;
      case 2: src = width_table; W = pW1 + 3392 * HID; bias = nullptr; rows = 17; o = tabs + 4352; break;
      case 3: src = rel_table;   W = pW1 + 3456 * HID; bias = nullptr; rows = 17; o = tabs + 6528; break;
      default:src = dep_table;   W = pW1 + 3520 * HID; bias = pb1;    rows = 30; o = tabs + 8704; break;
    }
    for (int e = tid; e < rows * HID; e += 256) {
      int r = e >> 7, c = e & 127;
      float acc = 0.f;
#pragma unroll 8
      for (int k = 0; k < 64; ++k) acc += src[r * 64 + k] * W[k * HID + c];
      o[e] = acc + (bias ? bias[c] : 0.f);
    }
  }
}

// ---------- kernel 2: split-K GEMM: part[ks] = X @ W6 (K chunk of 416) ----------
__global__ __launch_bounds__(256) void proj_gemm(
    const float* __restrict__ X, const float* __restrict__ sW1,
    const float* __restrict__ pW1, float* __restrict__ part) {
  int nt = blockIdx.x, mt = blockIdx.y, ks = blockIdx.z;
  const int f_offs[6] = {0, 768, 0, 768, 1728, 2496};
  const int p_offs[6] = {1536, 1600, 1536, 1600, 3264, 3328};
  int g = nt >> 1;
  const float* Wb = (g < 2) ? sW1 : pW1;
  int f_off = f_offs[g], p_off = p_offs[g];
  int c0 = (nt & 1) * 64;
  int row0 = mt * 64;
  int kbase = ks * 416;
  __shared__ float as[16][68];   // [k][row]
  __shared__ float bs[16][68];   // [k][col]
  int tid = threadIdx.x;
  int rg = tid >> 4, tc = tid & 15;
  float acc[4][4] = {{0.f}};
  for (int k0 = 0; k0 < 416; k0 += 16) {
    {
      int r = tid >> 2, kb = (tid & 3) * 4;
      float4 xv = *(const float4*)(X + (size_t)(row0 + r) * XLD + kbase + k0 + kb);
      as[kb + 0][r] = xv.x; as[kb + 1][r] = xv.y;
      as[kb + 2][r] = xv.z; as[kb + 3][r] = xv.w;
    }
    {
      int c = tid & 63, kq = tid >> 6;
#pragma unroll
      for (int q = 0; q < 4; ++q) {
        int kk = kq * 4 + q;
        int kg = kbase + k0 + kk;
        int wr = (kg < 768) ? (f_off + kg) : (p_off + kg - 768);
        bs[kk][c] = Wb[(size_t)wr * HID + c0 + c];
      }
    }
    __syncthreads();
#pragma unroll
    for (int kk = 0; kk < 16; ++kk) {
      float av[4], bv[4];
#pragma unroll
      for (int i = 0; i < 4; ++i) av[i] = as[kk][rg * 4 + i];
#pragma unroll
      for (int j = 0; j < 4; ++j) bv[j] = bs[kk][tc * 4 + j];
#pragma unroll
      for (int i = 0; i < 4; ++i)
#pragma unroll
        for (int j = 0; j < 4; ++j) acc[i][j] += av[i] * bv[j];
    }
    __syncthreads();
  }
#pragma unroll
  for (int i = 0; i < 4; ++i) {
    int row = row0 + rg * 4 + i;
    int bb = row >> 7, iloc = row & 127;
    float* dst = part + (size_t)ks * PROJ_N +
                 ((size_t)(g * BB + bb) * LW + iloc) * HID + c0 + tc * 4;
    *(float4*)dst = make_float4(acc[i][0], acc[i][1], acc[i][2], acc[i][3]);
  }
}

// ---------- kernel 3: span FFNN (32 spans/block), transposed-h LDS GEMM ----------
__global__ __launch_bounds__(256) void span_kernel(
    const float* __restrict__ part, const float* __restrict__ tabs,
    const float* __restrict__ sW2, const float* __restrict__ sb2,
    const float* __restrict__ sW3, const float* __restrict__ sb3,
    float* __restrict__ out) {
  int b = blockIdx.y, s0 = blockIdx.x * 32;
  int cnt = min(32, NSPANS - s0);
  __shared__ float hT[128][36];    // [col][row], stride 36 (16B aligned)
  __shared__ float wsh[16][132];
  __shared__ float w3s[384];
  __shared__ int stl[32], enl[32], wdl[32];
  int tid = threadIdx.x;
  if (tid < 32 && tid < cnt) {
    int st, en, w; span_decode(s0 + tid, st, en, w);
    stl[tid] = st; enl[tid] = en; wdl[tid] = w;
  }
  for (int i = tid; i < 384; i += 256) w3s[i] = sW3[i];
  __syncthreads();
  const float* SA0 = part + (size_t)(0 * BB + b) * LW * HID;
  const float* SB0 = part + (size_t)(1 * BB + b) * LW * HID;
  const float* SA1 = SA0 + PROJ_N;
  const float* SB1 = SB0 + PROJ_N;
  const float* SW = tabs;  // includes sb1
#pragma unroll
  for (int u = 0; u < 16; ++u) {
    int e = tid + u * 256; int r = e >> 7, c = e & 127;
    float v = 0.f;
    if (r < cnt) {
      int sa = stl[r] * HID + c, sb = enl[r] * HID + c;
      v = ((SA0[sa] + SA1[sa]) + (SB0[sb] + SB1[sb])) + SW[wdl[r] * HID + c];
    }
    hT[c][r] = fmaxf(v, 0.f);
  }
  __syncthreads();
  int rg = tid >> 5, tc = tid & 31;
  float acc[4][4] = {{0.f}};
  for (int k0 = 0; k0 < HID; k0 += 16) {
#pragma unroll
    for (int u = 0; u < 8; ++u) {
      int idx = tid + u * 256; int r = idx >> 7, c = idx & 127;
      wsh[r][c] = sW2[(k0 + r) * HID + c];
    }
    __syncthreads();
#pragma unroll
    for (int kk = 0; kk < 16; ++kk) {
      float4 a4 = *(const float4*)&hT[k0 + kk][rg * 4];
      float4 b4 = *(const float4*)&wsh[kk][tc * 4];
      float av[4] = {a4.x, a4.y, a4.z, a4.w};
      float bv[4] = {b4.x, b4.y, b4.z, b4.w};
#pragma unroll
      for (int i = 0; i < 4; ++i)
#pragma unroll
        for (int j = 0; j < 4; ++j) acc[i][j] += av[i] * bv[j];
    }
    __syncthreads();
  }
#pragma unroll
  for (int i = 0; i < 4; ++i)
#pragma unroll
    for (int j = 0; j < 4; ++j)
      hT[tc * 4 + j][rg * 4 + i] = fmaxf(acc[i][j] + sb2[tc * 4 + j], 0.f);
  __syncthreads();
  if (tid < 96) {
    int sl = tid / 3, oc = tid - sl * 3;
    if (sl < cnt) {
      float a = sb3[oc];
#pragma unroll 16
      for (int k = 0; k < HID; ++k) a += hT[k][sl] * w3s[k * 3 + oc];
      out[(b * NSPANS + s0 + sl) * 3 + oc] = a;
    }
  }
}

// ---------- kernel 4: pair FFNN with in-block dual rank-select top-64 ----------
struct PairShared {
  union {
    unsigned long long keys[2048];   // used as ulonglong2[996] (16 KB)
    float hT[128][68];               // 34.8 KB
  } u;
  float wsh[16][132];
  float w3[512];
  int mTA[64], mTB[64], mOA[64], mOB[64], mTW[64], mOW[64], mR[64], mD[64];
  int tixl[64], oixl[64];
};

__global__ __launch_bounds__(256) void pair_kernel(
    const float* __restrict__ part, const float* __restrict__ tabs,
    const int* __restrict__ dep_dis, const float* __restrict__ pW2,
    const float* __restrict__ pb2, const float* __restrict__ pW3,
    const float* __restrict__ pb3, float* __restrict__ out) {
  int b = blockIdx.y, p0 = blockIdx.x * 64;
  __shared__ __align__(16) PairShared sm;
  int tid = threadIdx.x;

  // ---- phase -1: dual rank-select top-64 (exact lax.top_k order, no sort) ----
  // key = (monotone(value) << 32) | (0xFFFFFFFF - e): unique => rank is a
  // permutation; dst[rank]=e for rank<64 == bitonic-sorted head, bit-exact.
  {
    ulonglong2* kp = (ulonglong2*)sm.u.keys;
    unsigned long long m1[4], m2[4];
#pragma unroll
    for (int uu = 0; uu < 4; ++uu) {
      int e = tid + uu * 256;
      unsigned long long kk1 = 0ull, kk2 = 0ull;
      if (e < NSPANS) {
        unsigned int b1 = __float_as_uint(out[(b * NSPANS + e) * 3 + 1]);
        unsigned int v1 = (b1 & 0x80000000u) ? ~b1 : (b1 | 0x80000000u);
        kk1 = ((unsigned long long)v1 << 32) | (unsigned long long)(0xFFFFFFFFu - e);
        unsigned int b2 = __float_as_uint(out[(b * NSPANS + e) * 3 + 2]);
        unsigned int v2 = (b2 & 0x80000000u) ? ~b2 : (b2 | 0x80000000u);
        kk2 = ((unsigned long long)v2 << 32) | (unsigned long long)(0xFFFFFFFFu - e);
        ulonglong2 kk; kk.x = kk1; kk.y = kk2;
        kp[e] = kk;
      }
      m1[uu] = kk1; m2[uu] = kk2;
    }
    __syncthreads();
    int r1[4] = {0, 0, 0, 0}, r2[4] = {0, 0, 0, 0};
#pragma unroll 4
    for (int j = 0; j < NSPANS; ++j) {
      ulonglong2 a = kp[j];            // broadcast ds_read_b128
#pragma unroll
      for (int uu = 0; uu < 4; ++uu) {
        r1[uu] += (a.x > m1[uu]) ? 1 : 0;
        r2[uu] += (a.y > m2[uu]) ? 1 : 0;
      }
    }
#pragma unroll
    for (int uu = 0; uu < 4; ++uu) {
      int e = tid + uu * 256;
      if (e < NSPANS) {
        if (r1[uu] < NZv) sm.tixl[r1[uu]] = e;
        if (r2[uu] < NZv) sm.oixl[r2[uu]] = e;
      }
    }
    __syncthreads();
  }

  // ---- phase 0: pair metadata (4 threads/pair) + stage w3 ----
  {
    sm.w3[tid] = pW3[tid]; sm.w3[tid + 256] = pW3[tid + 256];
    int m = tid >> 2, sub = tid & 3;
    int p = p0 + m;
    int ti = sm.tixl[p >> 6];
    int oi = sm.oixl[p & 63];
    int a, bb2, wt, c, d, wo;
    span_decode(ti, a, bb2, wt);
    span_decode(oi, c, d, wo);
    int mn = 0x7FFFFFFF;
    const int* dp = dep_dis + b * LW * LW;
    for (int x = a; x <= bb2; ++x)
      for (int y = c + sub; y <= d; y += 4)
        mn = min(mn, dp[x * LW + y]);
    mn = min(mn, __shfl_xor(mn, 1));
    mn = min(mn, __shfl_xor(mn, 2));
    if (sub == 0) {
      int rel = min(abs(bb2 - c), abs(a - d));
      sm.mTA[m] = ((2 * BB + b) * LW + a)   * HID;
      sm.mTB[m] = ((3 * BB + b) * LW + bb2) * HID;
      sm.mOA[m] = ((4 * BB + b) * LW + c)   * HID;
      sm.mOB[m] = ((5 * BB + b) * LW + d)   * HID;
      sm.mTW[m] = 2176 + wt * HID;
      sm.mOW[m] = 4352 + wo * HID;
      sm.mR[m]  = 6528 + bucket17(rel) * HID;
      sm.mD[m]  = 8704 + mn * HID;   // includes pb1
    }
  }
  __syncthreads();

  // ---- phase 1: h1 = relu(sum of 8 gathered vectors), transposed store ----
#pragma unroll
  for (int uu = 0; uu < 32; ++uu) {
    int e = tid + uu * 256; int r = e >> 7, c = e & 127;
    int ta = sm.mTA[r] + c, tb = sm.mTB[r] + c, oa = sm.mOA[r] + c, ob = sm.mOB[r] + c;
    float v = (part[ta] + part[ta + PROJ_N]) + (part[tb] + part[tb + PROJ_N]) +
              (part[oa] + part[oa + PROJ_N]) + (part[ob] + part[ob + PROJ_N]) +
              tabs[sm.mTW[r] + c] + tabs[sm.mOW[r] + c] +
              tabs[sm.mR[r] + c] + tabs[sm.mD[r] + c];
    sm.u.hT[c][r] = fmaxf(v, 0.f);
  }
  __syncthreads();

  // ---- phase 2: h2 = relu(h1 @ pW2 + pb2) ----
  int rg = tid >> 5, tc = tid & 31;
  float acc[8][4] = {{0.f}};
  for (int k0 = 0; k0 < HID; k0 += 16) {
#pragma unroll
    for (int uu = 0; uu < 8; ++uu) {
      int idx = tid + uu * 256; int r = idx >> 7, c = idx & 127;
      sm.wsh[r][c] = pW2[(k0 + r) * HID + c];
    }
    __syncthreads();
#pragma unroll
    for (int kk = 0; kk < 16; ++kk) {
      float4 a0 = *(const float4*)&sm.u.hT[k0 + kk][rg * 8];
      float4 a1 = *(const float4*)&sm.u.hT[k0 + kk][rg * 8 + 4];
      float4 b4 = *(const float4*)&sm.wsh[kk][tc * 4];
      float av[8] = {a0.x, a0.y, a0.z, a0.w, a1.x, a1.y, a1.z, a1.w};
      float bv[4] = {b4.x, b4.y, b4.z, b4.w};
#pragma unroll
      for (int i = 0; i < 8; ++i)
#pragma unroll
        for (int j = 0; j < 4; ++j) acc[i][j] += av[i] * bv[j];
    }
    __syncthreads();
  }
#pragma unroll
  for (int i = 0; i < 8; ++i)
#pragma unroll
    for (int j = 0; j < 4; ++j)
      sm.u.hT[tc * 4 + j][rg * 8 + i] = fmaxf(acc[i][j] + pb2[tc * 4 + j], 0.f);
  __syncthreads();

  // ---- phase 3: out4 = h2 @ pW3 + pb3 ----
  {
    int sl = tid >> 2, oc = tid & 3;
    float a = pb3[oc];
#pragma unroll 16
    for (int k = 0; k < HID; ++k) a += sm.u.hT[k][sl] * sm.w3[k * 4 + oc];
    out[BB * NSPANS * 3 + (b * NPAIR + p0 + sl) * 4 + oc] = a;
  }
}

extern "C" void kernel_launch(void* const* d_in, const int* in_sizes, int n_in,
                              void* d_out, int out_size, void* d_ws, size_t ws_size,
                              hipStream_t stream) {
  const float* last_hidden = (const float*)d_in[0];
  const float* mask        = (const float*)d_in[1];
  const float* word_len    = (const float*)d_in[2];
  const float* pos_table   = (const float*)d_in[3];
  const float* width_table = (const float*)d_in[4];
  const float* rel_table   = (const float*)d_in[5];
  const float* dep_table   = (const float*)d_in[6];
  const float* sW1 = (const float*)d_in[7];
  const float* sb1 = (const float*)d_in[8];
  const float* sW2 = (const float*)d_in[9];
  const float* sb2 = (const float*)d_in[10];
  const float* sW3 = (const float*)d_in[11];
  const float* sb3 = (const float*)d_in[12];
  const float* pW1 = (const float*)d_in[13];
  const float* pb1 = (const float*)d_in[14];
  const float* pW2 = (const float*)d_in[15];
  const float* pb2 = (const float*)d_in[16];
  const float* pW3 = (const float*)d_in[17];
  const float* pb3 = (const float*)d_in[18];
  const int* fss     = (const int*)d_in[19];
  const int* pos_id  = (const int*)d_in[20];
  const int* dep_dis = (const int*)d_in[21];

  float* ws   = (float*)d_ws;
  float* X    = ws;                       // 512*832  = 425984
  float* part = ws + 425984;              // 2*PROJ_N = 786432
  float* tabs = ws + 1212416;             // 12544
  float* out  = (float*)d_out;

  prep_kernel<<<109, 256, 0, stream>>>(mask, last_hidden, fss, word_len,
                                       pos_id, pos_table, width_table, rel_table,
                                       dep_table, sW1, pW1, sb1, pb1, X, tabs);
  proj_gemm<<<dim3(12, 8, 2), 256, 0, stream>>>(X, sW1, pW1, part);
  span_kernel<<<dim3(32, BB), 256, 0, stream>>>(part, tabs, sW2, sb2, sW3, sb3, out);
  pair_kernel<<<dim3(64, BB), 256, 0, stream>>>(part, tabs, dep_dis,
                                                pW2, pb2, pW3, pb3, out);
}

// Round 14
// 200.517 us; speedup vs baseline: 1.1964x; 1.1964x over previous
//
#include <hip/hip_runtime.h>

#define BB 4
#define LS 160
#define LW 128
#define DD 768
#define NSPANS 996
#define NZv 64
#define NPAIR 4096
#define HID 128
#define XLD 832          // X row stride: 768 feats + 64 pos
#define PROJ_N 393216    // 6*BB*LW*HID

// ---------- helpers ----------

__device__ inline void span_decode(int s, int& st, int& en, int& w) {
  int ww = 1, base = 0;
  while (ww < 8 && s >= base + (129 - ww)) { base += 129 - ww; ++ww; }
  st = s - base; en = st + ww - 1; w = ww;
}

__device__ inline int bucket17(int v) {
  const int BINSv[17] = {0,1,2,3,4,5,6,7,8,9,10,15,20,25,30,50,80};
  int r = 0;
#pragma unroll
  for (int k = 1; k < 17; ++k) r += (v >= BINSv[k]) ? 1 : 0;
  return r;
}

// ---------- kernel 1: prep = feats (96 blocks) + posfill (8) + smalltab (5) ----------
__global__ __launch_bounds__(256) void prep_kernel(
    const float* __restrict__ mask, const float* __restrict__ lh,
    const int* __restrict__ fss, const float* __restrict__ wlen,
    const int* __restrict__ pos_id, const float* __restrict__ pos_table,
    const float* __restrict__ width_table, const float* __restrict__ rel_table,
    const float* __restrict__ dep_table, const float* __restrict__ sW1,
    const float* __restrict__ pW1, const float* __restrict__ sb1,
    const float* __restrict__ pb1, float* __restrict__ X,
    float* __restrict__ tabs) {
  int gid = blockIdx.x;
  int tid = threadIdx.x;
  if (gid < 96) {
    int nt = gid % 12, mt = gid / 12;
    int b = mt >> 1;
    int row0 = mt * 64, c0 = nt * 64;
    __shared__ float as[16][68];   // [k][row]
    __shared__ float bs[16][68];   // [k][col]
    __shared__ int fssl[64];
    __shared__ float wll[64];
    if (tid < 64) { fssl[tid] = fss[row0 + tid]; wll[tid] = wlen[row0 + tid]; }
    __syncthreads();
    int rg = tid >> 4, tc = tid & 15;
    float acc[4][4] = {{0.f}};
    for (int k0 = 0; k0 < LS; k0 += 16) {
      {
        int r = tid >> 2, kb = (tid & 3) * 4;
        float4 mv = *(const float4*)(mask + (size_t)(b * LS + fssl[r]) * LS + k0 + kb);
        as[kb + 0][r] = mv.x; as[kb + 1][r] = mv.y;
        as[kb + 2][r] = mv.z; as[kb + 3][r] = mv.w;
      }
      {
        int c = tid & 63, kq = tid >> 6;
#pragma unroll
        for (int q = 0; q < 4; ++q) {
          int kk = kq * 4 + q;
          bs[kk][c] = lh[(size_t)(b * LS + k0 + kk) * DD + c0 + c];
        }
      }
      __syncthreads();
#pragma unroll
      for (int kk = 0; kk < 16; ++kk) {
        float av[4], bv[4];
#pragma unroll
        for (int i = 0; i < 4; ++i) av[i] = as[kk][rg * 4 + i];
#pragma unroll
        for (int j = 0; j < 4; ++j) bv[j] = bs[kk][tc * 4 + j];
#pragma unroll
        for (int i = 0; i < 4; ++i)
#pragma unroll
          for (int j = 0; j < 4; ++j) acc[i][j] += av[i] * bv[j];
      }
      __syncthreads();
    }
#pragma unroll
    for (int i = 0; i < 4; ++i) {
      int r = rg * 4 + i;
      float wl = wll[r];
      float4 v = make_float4(acc[i][0] / wl, acc[i][1] / wl, acc[i][2] / wl, acc[i][3] / wl);
      *(float4*)(X + (size_t)(row0 + r) * XLD + c0 + tc * 4) = v;
    }
  } else if (gid < 104) {
    int e0 = (gid - 96) * 4096 + tid * 16;
    int row = e0 >> 6, c0 = e0 & 63;
    const float* src = pos_table + pos_id[row] * 64 + c0;
    float* dst = X + (size_t)row * XLD + 768 + c0;
#pragma unroll
    for (int q = 0; q < 4; ++q)
      *(float4*)(dst + q * 4) = *(const float4*)(src + q * 4);
  } else {
    int bt = gid - 104;
    const float *src, *W, *bias; int rows; float* o;
    switch (bt) {
      case 0: src = width_table; W = sW1 + 1664 * HID; bias = sb1;    rows = 17; o = tabs;        break;
      case 1: src = width_table; W = pW1 + 1664 * HID; bias = nullptr; rows = 17; o = tabs + 2176; break;
      case 2: src = width_table; W = pW1 + 3392 * HID; bias = nullptr; rows = 17; o = tabs + 4352; break;
      case 3: src = rel_table;   W = pW1 + 3456 * HID; bias = nullptr; rows = 17; o = tabs + 6528; break;
      default:src = dep_table;   W = pW1 + 3520 * HID; bias = pb1;    rows = 30; o = tabs + 8704; break;
    }
    for (int e = tid; e < rows * HID; e += 256) {
      int r = e >> 7, c = e & 127;
      float acc = 0.f;
#pragma unroll 8
      for (int k = 0; k < 64; ++k) acc += src[r * 64 + k] * W[k * HID + c];
      o[e] = acc + (bias ? bias[c] : 0.f);
    }
  }
}

// ---------- kernel 2: split-K GEMM: part[ks] = X @ W6 (K chunk of 416) ----------
__global__ __launch_bounds__(256) void proj_gemm(
    const float* __restrict__ X, const float* __restrict__ sW1,
    const float* __restrict__ pW1, float* __restrict__ part) {
  int nt = blockIdx.x, mt = blockIdx.y, ks = blockIdx.z;
  const int f_offs[6] = {0, 768, 0, 768, 1728, 2496};
  const int p_offs[6] = {1536, 1600, 1536, 1600, 3264, 3328};
  int g = nt >> 1;
  const float* Wb = (g < 2) ? sW1 : pW1;
  int f_off = f_offs[g], p_off = p_offs[g];
  int c0 = (nt & 1) * 64;
  int row0 = mt * 64;
  int kbase = ks * 416;
  __shared__ float as[16][68];   // [k][row]
  __shared__ float bs[16][68];   // [k][col]
  int tid = threadIdx.x;
  int rg = tid >> 4, tc = tid & 15;
  float acc[4][4] = {{0.f}};
  for (int k0 = 0; k0 < 416; k0 += 16) {
    {
      int r = tid >> 2, kb = (tid & 3) * 4;
      float4 xv = *(const float4*)(X + (size_t)(row0 + r) * XLD + kbase + k0 + kb);
      as[kb + 0][r] = xv.x; as[kb + 1][r] = xv.y;
      as[kb + 2][r] = xv.z; as[kb + 3][r] = xv.w;
    }
    {
      int c = tid & 63, kq = tid >> 6;
#pragma unroll
      for (int q = 0; q < 4; ++q) {
        int kk = kq * 4 + q;
        int kg = kbase + k0 + kk;
        int wr = (kg < 768) ? (f_off + kg) : (p_off + kg - 768);
        bs[kk][c] = Wb[(size_t)wr * HID + c0 + c];
      }
    }
    __syncthreads();
#pragma unroll
    for (int kk = 0; kk < 16; ++kk) {
      float av[4], bv[4];
#pragma unroll
      for (int i = 0; i < 4; ++i) av[i] = as[kk][rg * 4 + i];
#pragma unroll
      for (int j = 0; j < 4; ++j) bv[j] = bs[kk][tc * 4 + j];
#pragma unroll
      for (int i = 0; i < 4; ++i)
#pragma unroll
        for (int j = 0; j < 4; ++j) acc[i][j] += av[i] * bv[j];
    }
    __syncthreads();
  }
#pragma unroll
  for (int i = 0; i < 4; ++i) {
    int row = row0 + rg * 4 + i;
    int bb = row >> 7, iloc = row & 127;
    float* dst = part + (size_t)ks * PROJ_N +
                 ((size_t)(g * BB + bb) * LW + iloc) * HID + c0 + tc * 4;
    *(float4*)dst = make_float4(acc[i][0], acc[i][1], acc[i][2], acc[i][3]);
  }
}

// ---------- kernel 3: span FFNN (32 spans/block), transposed-h LDS GEMM ----------
__global__ __launch_bounds__(256) void span_kernel(
    const float* __restrict__ part, const float* __restrict__ tabs,
    const float* __restrict__ sW2, const float* __restrict__ sb2,
    const float* __restrict__ sW3, const float* __restrict__ sb3,
    float* __restrict__ out) {
  int b = blockIdx.y, s0 = blockIdx.x * 32;
  int cnt = min(32, NSPANS - s0);
  __shared__ float hT[128][36];    // [col][row], stride 36 (16B aligned)
  __shared__ float wsh[16][132];
  __shared__ float w3s[384];
  __shared__ int stl[32], enl[32], wdl[32];
  int tid = threadIdx.x;
  if (tid < 32 && tid < cnt) {
    int st, en, w; span_decode(s0 + tid, st, en, w);
    stl[tid] = st; enl[tid] = en; wdl[tid] = w;
  }
  for (int i = tid; i < 384; i += 256) w3s[i] = sW3[i];
  __syncthreads();
  const float* SA0 = part + (size_t)(0 * BB + b) * LW * HID;
  const float* SB0 = part + (size_t)(1 * BB + b) * LW * HID;
  const float* SA1 = SA0 + PROJ_N;
  const float* SB1 = SB0 + PROJ_N;
  const float* SW = tabs;  // includes sb1
#pragma unroll
  for (int u = 0; u < 16; ++u) {
    int e = tid + u * 256; int r = e >> 7, c = e & 127;
    float v = 0.f;
    if (r < cnt) {
      int sa = stl[r] * HID + c, sb = enl[r] * HID + c;
      v = ((SA0[sa] + SA1[sa]) + (SB0[sb] + SB1[sb])) + SW[wdl[r] * HID + c];
    }
    hT[c][r] = fmaxf(v, 0.f);
  }
  __syncthreads();
  int rg = tid >> 5, tc = tid & 31;
  float acc[4][4] = {{0.f}};
  for (int k0 = 0; k0 < HID; k0 += 16) {
#pragma unroll
    for (int u = 0; u < 8; ++u) {
      int idx = tid + u * 256; int r = idx >> 7, c = idx & 127;
      wsh[r][c] = sW2[(k0 + r) * HID + c];
    }
    __syncthreads();
#pragma unroll
    for (int kk = 0; kk < 16; ++kk) {
      float4 a4 = *(const float4*)&hT[k0 + kk][rg * 4];
      float4 b4 = *(const float4*)&wsh[kk][tc * 4];
      float av[4] = {a4.x, a4.y, a4.z, a4.w};
      float bv[4] = {b4.x, b4.y, b4.z, b4.w};
#pragma unroll
      for (int i = 0; i < 4; ++i)
#pragma unroll
        for (int j = 0; j < 4; ++j) acc[i][j] += av[i] * bv[j];
    }
    __syncthreads();
  }
#pragma unroll
  for (int i = 0; i < 4; ++i)
#pragma unroll
    for (int j = 0; j < 4; ++j)
      hT[tc * 4 + j][rg * 4 + i] = fmaxf(acc[i][j] + sb2[tc * 4 + j], 0.f);
  __syncthreads();
  if (tid < 96) {
    int sl = tid / 3, oc = tid - sl * 3;
    if (sl < cnt) {
      float a = sb3[oc];
#pragma unroll 16
      for (int k = 0; k < HID; ++k) a += hT[k][sl] * w3s[k * 3 + oc];
      out[(b * NSPANS + s0 + sl) * 3 + oc] = a;
    }
  }
}

// ---------- kernel 4: parallel rank-select top-64 (exact lax.top_k order) ----------
// grid (8 chunks, 2 ch, 4 b), 256 threads. key = (monotone(v)<<32)|(~e):
// unique keys => rank is a permutation; dst[rank]=e for rank<64 is bit-exact.
// Thread t: element el = chunk*128 + (t>>1); scans half the j-range; halves
// merged via one shfl. LDS reads are 2-way broadcast (conflict-free).
__global__ __launch_bounds__(256) void topk_kernel(
    const float* __restrict__ out, int* __restrict__ tix, int* __restrict__ oix) {
  int chunk = blockIdx.x, ch = blockIdx.y + 1, b = blockIdx.z;
  int tid = threadIdx.x;
  __shared__ unsigned long long keys[1024];
#pragma unroll
  for (int u = 0; u < 4; ++u) {
    int e = tid + u * 256;
    unsigned long long kk = 0ull;
    if (e < NSPANS) {
      unsigned int bits = __float_as_uint(out[(b * NSPANS + e) * 3 + ch]);
      unsigned int mv = (bits & 0x80000000u) ? ~bits : (bits | 0x80000000u);
      kk = ((unsigned long long)mv << 32) | (unsigned long long)(0xFFFFFFFFu - e);
    }
    keys[e] = kk;
  }
  __syncthreads();
  int el = chunk * 128 + (tid >> 1);
  int half = tid & 1;
  unsigned long long myk = keys[el];
  int r = 0;
  int j0 = half * 498;
#pragma unroll 8
  for (int j = 0; j < 498; ++j)
    r += (keys[j0 + j] > myk) ? 1 : 0;
  r += __shfl_xor(r, 1);
  if (half == 0 && el < NSPANS && r < NZv) {
    int* dst = (ch == 1 ? tix : oix) + b * NZv;
    dst[r] = el;
  }
}

// ---------- kernel 5: pair FFNN, transposed-h LDS GEMM ----------
__global__ __launch_bounds__(256) void pair_kernel(
    const float* __restrict__ part, const float* __restrict__ tabs,
    const int* __restrict__ tix, const int* __restrict__ oix,
    const int* __restrict__ dep_dis, const float* __restrict__ pW2,
    const float* __restrict__ pb2, const float* __restrict__ pW3,
    const float* __restrict__ pb3, float* __restrict__ out) {
  int b = blockIdx.y, p0 = blockIdx.x * 64;
  __shared__ float hT[128][68];    // [col][row], stride 68 (16B aligned)
  __shared__ float wsh[16][132];
  __shared__ float w3[512];
  __shared__ int mTA[64], mTB[64], mOA[64], mOB[64], mTW[64], mOW[64], mR[64], mD[64];
  int tid = threadIdx.x;
  {
    w3[tid] = pW3[tid]; w3[tid + 256] = pW3[tid + 256];
    int m = tid >> 2, sub = tid & 3;
    int p = p0 + m;
    int ti = tix[b * NZv + (p >> 6)];
    int oi = oix[b * NZv + (p & 63)];
    int a, bb2, wt, c, d, wo;
    span_decode(ti, a, bb2, wt);
    span_decode(oi, c, d, wo);
    int mn = 0x7FFFFFFF;
    const int* dp = dep_dis + b * LW * LW;
    for (int x = a; x <= bb2; ++x)
      for (int y = c + sub; y <= d; y += 4)
        mn = min(mn, dp[x * LW + y]);
    mn = min(mn, __shfl_xor(mn, 1));
    mn = min(mn, __shfl_xor(mn, 2));
    if (sub == 0) {
      int rel = min(abs(bb2 - c), abs(a - d));
      mTA[m] = ((2 * BB + b) * LW + a)   * HID;
      mTB[m] = ((3 * BB + b) * LW + bb2) * HID;
      mOA[m] = ((4 * BB + b) * LW + c)   * HID;
      mOB[m] = ((5 * BB + b) * LW + d)   * HID;
      mTW[m] = 2176 + wt * HID;
      mOW[m] = 4352 + wo * HID;
      mR[m]  = 6528 + bucket17(rel) * HID;
      mD[m]  = 8704 + mn * HID;   // includes pb1
    }
  }
  __syncthreads();
#pragma unroll
  for (int u = 0; u < 32; ++u) {
    int e = tid + u * 256; int r = e >> 7, c = e & 127;
    int ta = mTA[r] + c, tb = mTB[r] + c, oa = mOA[r] + c, ob = mOB[r] + c;
    float v = (part[ta] + part[ta + PROJ_N]) + (part[tb] + part[tb + PROJ_N]) +
              (part[oa] + part[oa + PROJ_N]) + (part[ob] + part[ob + PROJ_N]) +
              tabs[mTW[r] + c] + tabs[mOW[r] + c] +
              tabs[mR[r] + c] + tabs[mD[r] + c];
    hT[c][r] = fmaxf(v, 0.f);
  }
  __syncthreads();
  int rg = tid >> 5, tc = tid & 31;
  float acc[8][4] = {{0.f}};
  for (int k0 = 0; k0 < HID; k0 += 16) {
#pragma unroll
    for (int u = 0; u < 8; ++u) {
      int idx = tid + u * 256; int r = idx >> 7, c = idx & 127;
      wsh[r][c] = pW2[(k0 + r) * HID + c];
    }
    __syncthreads();
#pragma unroll
    for (int kk = 0; kk < 16; ++kk) {
      float4 a0 = *(const float4*)&hT[k0 + kk][rg * 8];
      float4 a1 = *(const float4*)&hT[k0 + kk][rg * 8 + 4];
      float4 b4 = *(const float4*)&wsh[kk][tc * 4];
      float av[8] = {a0.x, a0.y, a0.z, a0.w, a1.x, a1.y, a1.z, a1.w};
      float bv[4] = {b4.x, b4.y, b4.z, b4.w};
#pragma unroll
      for (int i = 0; i < 8; ++i)
#pragma unroll
        for (int j = 0; j < 4; ++j) acc[i][j] += av[i] * bv[j];
    }
    __syncthreads();
  }
#pragma unroll
  for (int i = 0; i < 8; ++i)
#pragma unroll
    for (int j = 0; j < 4; ++j)
      hT[tc * 4 + j][rg * 8 + i] = fmaxf(acc[i][j] + pb2[tc * 4 + j], 0.f);
  __syncthreads();
  {
    int sl = tid >> 2, oc = tid & 3;
    float a = pb3[oc];
#pragma unroll 16
    for (int k = 0; k < HID; ++k) a += hT[k][sl] * w3[k * 4 + oc];
    out[BB * NSPANS * 3 + (b * NPAIR + p0 + sl) * 4 + oc] = a;
  }
}

extern "C" void kernel_launch(void* const* d_in, const int* in_sizes, int n_in,
                              void* d_out, int out_size, void* d_ws, size_t ws_size,
                              hipStream_t stream) {
  const float* last_hidden = (const float*)d_in[0];
  const float* mask        = (const float*)d_in[1];
  const float* word_len    = (const float*)d_in[2];
  const float* pos_table   = (const float*)d_in[3];
  const float* width_table = (const float*)d_in[4];
  const float* rel_table   = (const float*)d_in[5];
  const float* dep_table   = (const float*)d_in[6];
  const float* sW1 = (const float*)d_in[7];
  const float* sb1 = (const float*)d_in[8];
  const float* sW2 = (const float*)d_in[9];
  const float* sb2 = (const float*)d_in[10];
  const float* sW3 = (const float*)d_in[11];
  const float* sb3 = (const float*)d_in[12];
  const float* pW1 = (const float*)d_in[13];
  const float* pb1 = (const float*)d_in[14];
  const float* pW2 = (const float*)d_in[15];
  const float* pb2 = (const float*)d_in[16];
  const float* pW3 = (const float*)d_in[17];
  const float* pb3 = (const float*)d_in[18];
  const int* fss     = (const int*)d_in[19];
  const int* pos_id  = (const int*)d_in[20];
  const int* dep_dis = (const int*)d_in[21];

  float* ws   = (float*)d_ws;
  float* X    = ws;                       // 512*832  = 425984
  float* part = ws + 425984;              // 2*PROJ_N = 786432
  float* tabs = ws + 1212416;             // 12544
  int*   tix  = (int*)(ws + 1224960);     // 256
  int*   oix  = tix + 256;                // 256
  float* out  = (float*)d_out;

  prep_kernel<<<109, 256, 0, stream>>>(mask, last_hidden, fss, word_len,
                                       pos_id, pos_table, width_table, rel_table,
                                       dep_table, sW1, pW1, sb1, pb1, X, tabs);
  proj_gemm<<<dim3(12, 8, 2), 256, 0, stream>>>(X, sW1, pW1, part);
  span_kernel<<<dim3(32, BB), 256, 0, stream>>>(part, tabs, sW2, sb2, sW3, sb3, out);
  topk_kernel<<<dim3(8, 2, BB), 256, 0, stream>>>(out, tix, oix);
  pair_kernel<<<dim3(64, BB), 256, 0, stream>>>(part, tabs, tix, oix, dep_dis,
                                                pW2, pb2, pW3, pb3, out);
}

// Round 15
// 195.603 us; speedup vs baseline: 1.2265x; 1.0251x over previous
//
#include <hip/hip_runtime.h>

#define BB 4
#define LS 160
#define LW 128
#define DD 768
#define NSPANS 996
#define NZv 64
#define NPAIR 4096
#define HID 128
#define XLD 832          // X row stride: 768 feats + 64 pos
#define PROJ_N 393216    // 6*BB*LW*HID
#define KSPLIT 4
#define KCH 208          // 832 / 4

// ---------- helpers ----------

__device__ inline void span_decode(int s, int& st, int& en, int& w) {
  int ww = 1, base = 0;
  while (ww < 8 && s >= base + (129 - ww)) { base += 129 - ww; ++ww; }
  st = s - base; en = st + ww - 1; w = ww;
}

__device__ inline int bucket17(int v) {
  const int BINSv[17] = {0,1,2,3,4,5,6,7,8,9,10,15,20,25,30,50,80};
  int r = 0;
#pragma unroll
  for (int k = 1; k < 17; ++k) r += (v >= BINSv[k]) ? 1 : 0;
  return r;
}

__device__ inline float sum4(const float* __restrict__ part, int idx) {
  return (part[idx] + part[idx + PROJ_N]) +
         (part[idx + 2 * PROJ_N] + part[idx + 3 * PROJ_N]);
}

// ---------- kernel 1: prep = feats (96 blocks) + posfill (8) + smalltab (5) ----------
__global__ __launch_bounds__(256) void prep_kernel(
    const float* __restrict__ mask, const float* __restrict__ lh,
    const int* __restrict__ fss, const float* __restrict__ wlen,
    const int* __restrict__ pos_id, const float* __restrict__ pos_table,
    const float* __restrict__ width_table, const float* __restrict__ rel_table,
    const float* __restrict__ dep_table, const float* __restrict__ sW1,
    const float* __restrict__ pW1, const float* __restrict__ sb1,
    const float* __restrict__ pb1, float* __restrict__ X,
    float* __restrict__ tabs) {
  int gid = blockIdx.x;
  int tid = threadIdx.x;
  if (gid < 96) {
    int nt = gid % 12, mt = gid / 12;
    int b = mt >> 1;
    int row0 = mt * 64, c0 = nt * 64;
    __shared__ float as[16][68];   // [k][row]
    __shared__ float bs[16][68];   // [k][col]
    __shared__ int fssl[64];
    __shared__ float wll[64];
    if (tid < 64) { fssl[tid] = fss[row0 + tid]; wll[tid] = wlen[row0 + tid]; }
    __syncthreads();
    int rg = tid >> 4, tc = tid & 15;
    float acc[4][4] = {{0.f}};
    for (int k0 = 0; k0 < LS; k0 += 16) {
      {
        int r = tid >> 2, kb = (tid & 3) * 4;
        float4 mv = *(const float4*)(mask + (size_t)(b * LS + fssl[r]) * LS + k0 + kb);
        as[kb + 0][r] = mv.x; as[kb + 1][r] = mv.y;
        as[kb + 2][r] = mv.z; as[kb + 3][r] = mv.w;
      }
      {
        int c = tid & 63, kq = tid >> 6;
#pragma unroll
        for (int q = 0; q < 4; ++q) {
          int kk = kq * 4 + q;
          bs[kk][c] = lh[(size_t)(b * LS + k0 + kk) * DD + c0 + c];
        }
      }
      __syncthreads();
#pragma unroll
      for (int kk = 0; kk < 16; ++kk) {
        float av[4], bv[4];
#pragma unroll
        for (int i = 0; i < 4; ++i) av[i] = as[kk][rg * 4 + i];
#pragma unroll
        for (int j = 0; j < 4; ++j) bv[j] = bs[kk][tc * 4 + j];
#pragma unroll
        for (int i = 0; i < 4; ++i)
#pragma unroll
          for (int j = 0; j < 4; ++j) acc[i][j] += av[i] * bv[j];
      }
      __syncthreads();
    }
#pragma unroll
    for (int i = 0; i < 4; ++i) {
      int r = rg * 4 + i;
      float wl = wll[r];
      float4 v = make_float4(acc[i][0] / wl, acc[i][1] / wl, acc[i][2] / wl, acc[i][3] / wl);
      *(float4*)(X + (size_t)(row0 + r) * XLD + c0 + tc * 4) = v;
    }
  } else if (gid < 104) {
    int e0 = (gid - 96) * 4096 + tid * 16;
    int row = e0 >> 6, c0 = e0 & 63;
    const float* src = pos_table + pos_id[row] * 64 + c0;
    float* dst = X + (size_t)row * XLD + 768 + c0;
#pragma unroll
    for (int q = 0; q < 4; ++q)
      *(float4*)(dst + q * 4) = *(const float4*)(src + q * 4);
  } else {
    int bt = gid - 104;
    const float *src, *W, *bias; int rows; float* o;
    switch (bt) {
      case 0: src = width_table; W = sW1 + 1664 * HID; bias = sb1;    rows = 17; o = tabs;        break;
      case 1: src = width_table; W = pW1 + 1664 * HID; bias = nullptr; rows = 17; o = tabs + 2176; break;
      case 2: src = width_table; W = pW1 + 3392 * HID; bias = nullptr; rows = 17; o = tabs + 4352; break;
      case 3: src = rel_table;   W = pW1 + 3456 * HID; bias = nullptr; rows = 17; o = tabs + 6528; break;
      default:src = dep_table;   W = pW1 + 3520 * HID; bias = pb1;    rows = 30; o = tabs + 8704; break;
    }
    for (int e = tid; e < rows * HID; e += 256) {
      int r = e >> 7, c = e & 127;
      float acc = 0.f;
#pragma unroll 8
      for (int k = 0; k < 64; ++k) acc += src[r * 64 + k] * W[k * HID + c];
      o[e] = acc + (bias ? bias[c] : 0.f);
    }
  }
}

// ---------- kernel 2: split-K(4) GEMM: part[ks] = X @ W6 (K chunk of 208) ----------
__global__ __launch_bounds__(256) void proj_gemm(
    const float* __restrict__ X, const float* __restrict__ sW1,
    const float* __restrict__ pW1, float* __restrict__ part) {
  int nt = blockIdx.x, mt = blockIdx.y, ks = blockIdx.z;
  const int f_offs[6] = {0, 768, 0, 768, 1728, 2496};
  const int p_offs[6] = {1536, 1600, 1536, 1600, 3264, 3328};
  int g = nt >> 1;
  const float* Wb = (g < 2) ? sW1 : pW1;
  int f_off = f_offs[g], p_off = p_offs[g];
  int c0 = (nt & 1) * 64;
  int row0 = mt * 64;
  int kbase = ks * KCH;
  __shared__ float as[16][68];   // [k][row]
  __shared__ float bs[16][68];   // [k][col]
  int tid = threadIdx.x;
  int rg = tid >> 4, tc = tid & 15;
  float acc[4][4] = {{0.f}};
  for (int k0 = 0; k0 < KCH; k0 += 16) {
    {
      int r = tid >> 2, kb = (tid & 3) * 4;
      float4 xv = *(const float4*)(X + (size_t)(row0 + r) * XLD + kbase + k0 + kb);
      as[kb + 0][r] = xv.x; as[kb + 1][r] = xv.y;
      as[kb + 2][r] = xv.z; as[kb + 3][r] = xv.w;
    }
    {
      int c = tid & 63, kq = tid >> 6;
#pragma unroll
      for (int q = 0; q < 4; ++q) {
        int kk = kq * 4 + q;
        int kg = kbase + k0 + kk;
        int wr = (kg < 768) ? (f_off + kg) : (p_off + kg - 768);
        bs[kk][c] = Wb[(size_t)wr * HID + c0 + c];
      }
    }
    __syncthreads();
#pragma unroll
    for (int kk = 0; kk < 16; ++kk) {
      float av[4], bv[4];
#pragma unroll
      for (int i = 0; i < 4; ++i) av[i] = as[kk][rg * 4 + i];
#pragma unroll
      for (int j = 0; j < 4; ++j) bv[j] = bs[kk][tc * 4 + j];
#pragma unroll
      for (int i = 0; i < 4; ++i)
#pragma unroll
        for (int j = 0; j < 4; ++j) acc[i][j] += av[i] * bv[j];
    }
    __syncthreads();
  }
#pragma unroll
  for (int i = 0; i < 4; ++i) {
    int row = row0 + rg * 4 + i;
    int bb = row >> 7, iloc = row & 127;
    float* dst = part + (size_t)ks * PROJ_N +
                 ((size_t)(g * BB + bb) * LW + iloc) * HID + c0 + tc * 4;
    *(float4*)dst = make_float4(acc[i][0], acc[i][1], acc[i][2], acc[i][3]);
  }
}

// ---------- kernel 3: span FFNN (32 spans/block), transposed-h LDS GEMM ----------
__global__ __launch_bounds__(256) void span_kernel(
    const float* __restrict__ part, const float* __restrict__ tabs,
    const float* __restrict__ sW2, const float* __restrict__ sb2,
    const float* __restrict__ sW3, const float* __restrict__ sb3,
    float* __restrict__ out) {
  int b = blockIdx.y, s0 = blockIdx.x * 32;
  int cnt = min(32, NSPANS - s0);
  __shared__ float hT[128][36];    // [col][row], stride 36 (16B aligned)
  __shared__ float wsh[16][132];
  __shared__ float w3s[384];
  __shared__ int stl[32], enl[32], wdl[32];
  int tid = threadIdx.x;
  if (tid < 32 && tid < cnt) {
    int st, en, w; span_decode(s0 + tid, st, en, w);
    stl[tid] = st; enl[tid] = en; wdl[tid] = w;
  }
  for (int i = tid; i < 384; i += 256) w3s[i] = sW3[i];
  __syncthreads();
  int baseA = (0 * BB + b) * LW * HID;
  int baseB = (1 * BB + b) * LW * HID;
  const float* SW = tabs;  // includes sb1
#pragma unroll
  for (int u = 0; u < 16; ++u) {
    int e = tid + u * 256; int r = e >> 7, c = e & 127;
    float v = 0.f;
    if (r < cnt) {
      int sa = baseA + stl[r] * HID + c, sb = baseB + enl[r] * HID + c;
      v = (sum4(part, sa) + sum4(part, sb)) + SW[wdl[r] * HID + c];
    }
    hT[c][r] = fmaxf(v, 0.f);
  }
  __syncthreads();
  int rg = tid >> 5, tc = tid & 31;
  float acc[4][4] = {{0.f}};
  for (int k0 = 0; k0 < HID; k0 += 16) {
#pragma unroll
    for (int u = 0; u < 8; ++u) {
      int idx = tid + u * 256; int r = idx >> 7, c = idx & 127;
      wsh[r][c] = sW2[(k0 + r) * HID + c];
    }
    __syncthreads();
#pragma unroll
    for (int kk = 0; kk < 16; ++kk) {
      float4 a4 = *(const float4*)&hT[k0 + kk][rg * 4];
      float4 b4 = *(const float4*)&wsh[kk][tc * 4];
      float av[4] = {a4.x, a4.y, a4.z, a4.w};
      float bv[4] = {b4.x, b4.y, b4.z, b4.w};
#pragma unroll
      for (int i = 0; i < 4; ++i)
#pragma unroll
        for (int j = 0; j < 4; ++j) acc[i][j] += av[i] * bv[j];
    }
    __syncthreads();
  }
#pragma unroll
  for (int i = 0; i < 4; ++i)
#pragma unroll
    for (int j = 0; j < 4; ++j)
      hT[tc * 4 + j][rg * 4 + i] = fmaxf(acc[i][j] + sb2[tc * 4 + j], 0.f);
  __syncthreads();
  if (tid < 96) {
    int sl = tid / 3, oc = tid - sl * 3;
    if (sl < cnt) {
      float a = sb3[oc];
#pragma unroll 16
      for (int k = 0; k < HID; ++k) a += hT[k][sl] * w3s[k * 3 + oc];
      out[(b * NSPANS + s0 + sl) * 3 + oc] = a;
    }
  }
}

// ---------- kernel 4: parallel rank-select top-64 (exact lax.top_k order) ----------
__global__ __launch_bounds__(256) void topk_kernel(
    const float* __restrict__ out, int* __restrict__ tix, int* __restrict__ oix) {
  int chunk = blockIdx.x, ch = blockIdx.y + 1, b = blockIdx.z;
  int tid = threadIdx.x;
  __shared__ unsigned long long keys[1024];
#pragma unroll
  for (int u = 0; u < 4; ++u) {
    int e = tid + u * 256;
    unsigned long long kk = 0ull;
    if (e < NSPANS) {
      unsigned int bits = __float_as_uint(out[(b * NSPANS + e) * 3 + ch]);
      unsigned int mv = (bits & 0x80000000u) ? ~bits : (bits | 0x80000000u);
      kk = ((unsigned long long)mv << 32) | (unsigned long long)(0xFFFFFFFFu - e);
    }
    keys[e] = kk;
  }
  __syncthreads();
  int el = chunk * 128 + (tid >> 1);
  int half = tid & 1;
  unsigned long long myk = keys[el];
  int r = 0;
  int j0 = half * 498;
#pragma unroll 8
  for (int j = 0; j < 498; ++j)
    r += (keys[j0 + j] > myk) ? 1 : 0;
  r += __shfl_xor(r, 1);
  if (half == 0 && el < NSPANS && r < NZv) {
    int* dst = (ch == 1 ? tix : oix) + b * NZv;
    dst[r] = el;
  }
}

// ---------- kernel 5: pair FFNN, transposed-h LDS GEMM ----------
__global__ __launch_bounds__(256) void pair_kernel(
    const float* __restrict__ part, const float* __restrict__ tabs,
    const int* __restrict__ tix, const int* __restrict__ oix,
    const int* __restrict__ dep_dis, const float* __restrict__ pW2,
    const float* __restrict__ pb2, const float* __restrict__ pW3,
    const float* __restrict__ pb3, float* __restrict__ out) {
  int b = blockIdx.y, p0 = blockIdx.x * 64;
  __shared__ float hT[128][68];    // [col][row], stride 68 (16B aligned)
  __shared__ float wsh[16][132];
  __shared__ float w3[512];
  __shared__ int mTA[64], mTB[64], mOA[64], mOB[64], mTW[64], mOW[64], mR[64], mD[64];
  int tid = threadIdx.x;
  {
    w3[tid] = pW3[tid]; w3[tid + 256] = pW3[tid + 256];
    int m = tid >> 2, sub = tid & 3;
    int p = p0 + m;
    int ti = tix[b * NZv + (p >> 6)];
    int oi = oix[b * NZv + (p & 63)];
    int a, bb2, wt, c, d, wo;
    span_decode(ti, a, bb2, wt);
    span_decode(oi, c, d, wo);
    int mn = 0x7FFFFFFF;
    const int* dp = dep_dis + b * LW * LW;
    for (int x = a; x <= bb2; ++x)
      for (int y = c + sub; y <= d; y += 4)
        mn = min(mn, dp[x * LW + y]);
    mn = min(mn, __shfl_xor(mn, 1));
    mn = min(mn, __shfl_xor(mn, 2));
    if (sub == 0) {
      int rel = min(abs(bb2 - c), abs(a - d));
      mTA[m] = ((2 * BB + b) * LW + a)   * HID;
      mTB[m] = ((3 * BB + b) * LW + bb2) * HID;
      mOA[m] = ((4 * BB + b) * LW + c)   * HID;
      mOB[m] = ((5 * BB + b) * LW + d)   * HID;
      mTW[m] = 2176 + wt * HID;
      mOW[m] = 4352 + wo * HID;
      mR[m]  = 6528 + bucket17(rel) * HID;
      mD[m]  = 8704 + mn * HID;   // includes pb1
    }
  }
  __syncthreads();
#pragma unroll
  for (int u = 0; u < 32; ++u) {
    int e = tid + u * 256; int r = e >> 7, c = e & 127;
    float v = (sum4(part, mTA[r] + c) + sum4(part, mTB[r] + c)) +
              (sum4(part, mOA[r] + c) + sum4(part, mOB[r] + c)) +
              tabs[mTW[r] + c] + tabs[mOW[r] + c] +
              tabs[mR[r] + c] + tabs[mD[r] + c];
    hT[c][r] = fmaxf(v, 0.f);
  }
  __syncthreads();
  int rg = tid >> 5, tc = tid & 31;
  float acc[8][4] = {{0.f}};
  for (int k0 = 0; k0 < HID; k0 += 16) {
#pragma unroll
    for (int u = 0; u < 8; ++u) {
      int idx = tid + u * 256; int r = idx >> 7, c = idx & 127;
      wsh[r][c] = pW2[(k0 + r) * HID + c];
    }
    __syncthreads();
#pragma unroll
    for (int kk = 0; kk < 16; ++kk) {
      float4 a0 = *(const float4*)&hT[k0 + kk][rg * 8];
      float4 a1 = *(const float4*)&hT[k0 + kk][rg * 8 + 4];
      float4 b4 = *(const float4*)&wsh[kk][tc * 4];
      float av[8] = {a0.x, a0.y, a0.z, a0.w, a1.x, a1.y, a1.z, a1.w};
      float bv[4] = {b4.x, b4.y, b4.z, b4.w};
#pragma unroll
      for (int i = 0; i < 8; ++i)
#pragma unroll
        for (int j = 0; j < 4; ++j) acc[i][j] += av[i] * bv[j];
    }
    __syncthreads();
  }
#pragma unroll
  for (int i = 0; i < 8; ++i)
#pragma unroll
    for (int j = 0; j < 4; ++j)
      hT[tc * 4 + j][rg * 8 + i] = fmaxf(acc[i][j] + pb2[tc * 4 + j], 0.f);
  __syncthreads();
  {
    int sl = tid >> 2, oc = tid & 3;
    float a = pb3[oc];
#pragma unroll 16
    for (int k = 0; k < HID; ++k) a += hT[k][sl] * w3[k * 4 + oc];
    out[BB * NSPANS * 3 + (b * NPAIR + p0 + sl) * 4 + oc] = a;
  }
}

extern "C" void kernel_launch(void* const* d_in, const int* in_sizes, int n_in,
                              void* d_out, int out_size, void* d_ws, size_t ws_size,
                              hipStream_t stream) {
  const float* last_hidden = (const float*)d_in[0];
  const float* mask        = (const float*)d_in[1];
  const float* word_len    = (const float*)d_in[2];
  const float* pos_table   = (const float*)d_in[3];
  const float* width_table = (const float*)d_in[4];
  const float* rel_table   = (const float*)d_in[5];
  const float* dep_table   = (const float*)d_in[6];
  const float* sW1 = (const float*)d_in[7];
  const float* sb1 = (const float*)d_in[8];
  const float* sW2 = (const float*)d_in[9];
  const float* sb2 = (const float*)d_in[10];
  const float* sW3 = (const float*)d_in[11];
  const float* sb3 = (const float*)d_in[12];
  const float* pW1 = (const float*)d_in[13];
  const float* pb1 = (const float*)d_in[14];
  const float* pW2 = (const float*)d_in[15];
  const float* pb2 = (const float*)d_in[16];
  const float* pW3 = (const float*)d_in[17];
  const float* pb3 = (const float*)d_in[18];
  const int* fss     = (const int*)d_in[19];
  const int* pos_id  = (const int*)d_in[20];
  const int* dep_dis = (const int*)d_in[21];

  float* ws   = (float*)d_ws;
  float* X    = ws;                       // 512*832       = 425984
  float* part = ws + 425984;              // 4*PROJ_N      = 1572864
  float* tabs = ws + 1998848;             // 12544
  int*   tix  = (int*)(ws + 2011392);     // 256
  int*   oix  = tix + 256;                // 256
  float* out  = (float*)d_out;

  prep_kernel<<<109, 256, 0, stream>>>(mask, last_hidden, fss, word_len,
                                       pos_id, pos_table, width_table, rel_table,
                                       dep_table, sW1, pW1, sb1, pb1, X, tabs);
  proj_gemm<<<dim3(12, 8, KSPLIT), 256, 0, stream>>>(X, sW1, pW1, part);
  span_kernel<<<dim3(32, BB), 256, 0, stream>>>(part, tabs, sW2, sb2, sW3, sb3, out);
  topk_kernel<<<dim3(8, 2, BB), 256, 0, stream>>>(out, tix, oix);
  pair_kernel<<<dim3(64, BB), 256, 0, stream>>>(part, tabs, tix, oix, dep_dis,
                                                pW2, pb2, pW3, pb3, out);
}